// Round 3
// baseline (161.876 us; speedup 1.0000x reference)
//
#include <hip/hip_runtime.h>
#include <math.h>

#define RAD 5
#define SIDE 80
#define SLAB 6400      // 80*80
#define VOL 512000     // 80^3
#define NCH 8          // N*K
#define NCLS 4

// exp(-t^2/32) for t=-5..5 (unnormalized Gaussian, symmetric)
__constant__ float GW[11] = {
    0.45783336177161427f, 0.6065306597126334f, 0.7548396019890073f,
    0.8824969025845955f,  0.969233234476344f,  1.0f,
    0.969233234476344f,   0.8824969025845955f, 0.7548396019890073f,
    0.6065306597126334f,  0.45783336177161427f};

// Module-scope scratch: no dependence on d_ws at all (allocated at module load).
// g_acc: [0..15] = {S_ip, S_p} per channel; [16..31] = {num, den} per channel.
// g_buf: separable conv of labels, one channel field (16.38 MB).
__device__ float g_acc[32];
__device__ float g_buf[(size_t)NCH * VOL];

__global__ void zero_acc_kernel() {
    if (threadIdx.x < 32) g_acc[threadIdx.x] = 0.0f;
}

// Per-channel sums: S_ip = sum(lab*img), S_p = sum(lab)
__global__ void sums_kernel(const float* __restrict__ labels,
                            const float* __restrict__ img) {
    const int c = blockIdx.y;      // 0..7 = n*4+k
    const int n = c >> 2;
    const float4* lab4 = (const float4*)(labels + (size_t)c * VOL);
    const float4* img4 = (const float4*)(img + (size_t)n * VOL);
    float sip = 0.f, sp = 0.f;
    const int stride = gridDim.x * blockDim.x;
    for (int i = blockIdx.x * blockDim.x + threadIdx.x; i < VOL / 4; i += stride) {
        float4 l = lab4[i];
        float4 v = img4[i];
        sip += l.x * v.x + l.y * v.y + l.z * v.z + l.w * v.w;
        sp  += l.x + l.y + l.z + l.w;
    }
    #pragma unroll
    for (int off = 32; off > 0; off >>= 1) {
        sip += __shfl_down(sip, off);
        sp  += __shfl_down(sp, off);
    }
    __shared__ float sm[8];
    const int lane = threadIdx.x & 63;
    const int wid  = threadIdx.x >> 6;
    if (lane == 0) { sm[wid * 2] = sip; sm[wid * 2 + 1] = sp; }
    __syncthreads();
    if (threadIdx.x == 0) {
        atomicAdd(&g_acc[2 * c],     sm[0] + sm[2] + sm[4] + sm[6]);
        atomicAdd(&g_acc[2 * c + 1], sm[1] + sm[3] + sm[5] + sm[7]);
    }
}

// Conv of labels along D (innermost). One block per (c,h) slab of 80x80.
__global__ void convd_kernel(const float* __restrict__ labels) {
    const int blk = blockIdx.x;          // c*SIDE + h
    __shared__ float tile[SLAB];         // [w][d]
    const float* src = labels + (size_t)blk * SLAB;
    for (int i = threadIdx.x; i < SLAB; i += blockDim.x) tile[i] = src[i];
    __syncthreads();
    float* out = g_buf + (size_t)blk * SLAB;
    for (int i = threadIdx.x; i < SLAB; i += blockDim.x) {
        const int d = i % SIDE;
        float s = 0.f;
        #pragma unroll
        for (int t = -RAD; t <= RAD; ++t) {
            int dd = d + t;
            if (dd >= 0 && dd < SIDE) s += GW[t + RAD] * tile[i + t];
        }
        out[i] = s;
    }
}

// Conv along W, in-place (block owns the whole (c,h) slab in LDS before writing)
__global__ void convw_kernel() {
    const int blk = blockIdx.x;      // c*SIDE + h
    __shared__ float tile[SLAB];
    float* p = g_buf + (size_t)blk * SLAB;
    for (int i = threadIdx.x; i < SLAB; i += blockDim.x) tile[i] = p[i];
    __syncthreads();
    for (int i = threadIdx.x; i < SLAB; i += blockDim.x) {
        const int w = i / SIDE;
        float s = 0.f;
        #pragma unroll
        for (int t = -RAD; t <= RAD; ++t) {
            int ww = w + t;
            if (ww >= 0 && ww < SIDE) s += GW[t + RAD] * tile[i + t * SIDE];
        }
        p[i] = s;
    }
}

// Conv along H + fused weight + dot. Block per (c,w) slab.
// num_c = sum (G*lab)·lab·wgt ; den_c = sum (G*lab)·wgt
// where wgt = exp(-(img-mean_c)^4)  [symmetric-kernel identity]
__global__ void convh_dot_kernel(const float* __restrict__ labels,
                                 const float* __restrict__ img) {
    const int blk = blockIdx.x;      // c*SIDE + w
    const int c = blk / SIDE;
    const int w = blk % SIDE;
    const int n = c >> 2;
    const float mean = g_acc[2 * c] / (g_acc[2 * c + 1] + 5.12f);  // VOL*EPS_MEAN
    __shared__ float tile[SLAB];     // [h][d] of conv'd labels, gathered at fixed w
    const float* bp = g_buf + (size_t)c * VOL;
    for (int i = threadIdx.x; i < SLAB; i += blockDim.x) {
        int h = i / SIDE, d = i - h * SIDE;
        tile[i] = bp[((size_t)h * SIDE + w) * SIDE + d];
    }
    __syncthreads();
    const float* labp = labels + (size_t)c * VOL;
    const float* imgp = img + (size_t)n * VOL;
    float num = 0.f, den = 0.f;
    for (int i = threadIdx.x; i < SLAB; i += blockDim.x) {
        int h = i / SIDE, d = i - h * SIDE;
        float s = 0.f;
        #pragma unroll
        for (int t = -RAD; t <= RAD; ++t) {
            int hh = h + t;
            if (hh >= 0 && hh < SIDE) s += GW[t + RAD] * tile[i + t * SIDE];
        }
        size_t gi = ((size_t)h * SIDE + w) * SIDE + d;
        float l = labp[gi];
        float v = imgp[gi];
        float df = v - mean;
        float d2 = df * df;
        float wgt = __expf(-d2 * d2);     // exp(-(img-mean)^4)
        num += s * l * wgt;
        den += s * wgt;
    }
    #pragma unroll
    for (int off = 32; off > 0; off >>= 1) {
        num += __shfl_down(num, off);
        den += __shfl_down(den, off);
    }
    __shared__ float sm[8];
    const int lane = threadIdx.x & 63;
    const int wid  = threadIdx.x >> 6;
    if (lane == 0) { sm[wid * 2] = num; sm[wid * 2 + 1] = den; }
    __syncthreads();
    if (threadIdx.x == 0) {
        atomicAdd(&g_acc[16 + 2 * c], sm[0] + sm[2] + sm[4] + sm[6]);
        atomicAdd(&g_acc[17 + 2 * c], sm[1] + sm[3] + sm[5] + sm[7]);
    }
}

__global__ void final_kernel(float* __restrict__ out) {
    if (threadIdx.x == 0) {
        float loss = 0.f;
        for (int k = 0; k < NCLS; ++k) {
            float r0 = g_acc[16 + 2 * k]          / (g_acc[17 + 2 * k] + 1e-6f);
            float r1 = g_acc[16 + 2 * (NCLS + k)] / (g_acc[17 + 2 * (NCLS + k)] + 1e-6f);
            loss += 0.5f * (fabsf(r0) + fabsf(r1));   // mean over N=2, sum over K
        }
        out[0] = (float)NCLS - loss;
    }
}

extern "C" void kernel_launch(void* const* d_in, const int* in_sizes, int n_in,
                              void* d_out, int out_size, void* d_ws, size_t ws_size,
                              hipStream_t stream) {
    const float* labels = (const float*)d_in[0];   // (2,4,80,80,80) f32
    const float* img    = (const float*)d_in[1];   // (2,1,80,80,80) f32
    float* out = (float*)d_out;                    // 1 float
    (void)d_ws; (void)ws_size;                     // unused — module-scope scratch

    hipLaunchKernelGGL(zero_acc_kernel, dim3(1), dim3(64), 0, stream);
    hipLaunchKernelGGL(sums_kernel, dim3(32, NCH), dim3(256), 0, stream, labels, img);
    hipLaunchKernelGGL(convd_kernel, dim3(NCH * SIDE), dim3(256), 0, stream, labels);
    hipLaunchKernelGGL(convw_kernel, dim3(NCH * SIDE), dim3(256), 0, stream);
    hipLaunchKernelGGL(convh_dot_kernel, dim3(NCH * SIDE), dim3(256), 0, stream, labels, img);
    hipLaunchKernelGGL(final_kernel, dim3(1), dim3(64), 0, stream, out);
}

// Round 4
// 131.533 us; speedup vs baseline: 1.2307x; 1.2307x over previous
//
#include <hip/hip_runtime.h>
#include <math.h>

#define RAD 5
#define SIDE 80
#define SLAB 6400      // 80*80
#define VOL 512000     // 80^3
#define NCH 8          // N*K
#define NCLS 4

// exp(-t^2/32) for t=-5..5 (unnormalized Gaussian, symmetric)
__constant__ float GW[11] = {
    0.45783336177161427f, 0.6065306597126334f, 0.7548396019890073f,
    0.8824969025845955f,  0.969233234476344f,  1.0f,
    0.969233234476344f,   0.8824969025845955f, 0.7548396019890073f,
    0.6065306597126334f,  0.45783336177161427f};

// Module-scope scratch (no d_ws dependence).
// g_acc: [0..15] = {S_ip, S_p} per channel; [16..31] = {num, den} per channel.
// g_bufT: d+w-convolved labels, TRANSPOSED layout [c][w][h][d] (16.38 MB).
__device__ float g_acc[32];
__device__ float g_bufT[(size_t)NCH * VOL];

__global__ void zero_acc_kernel() {
    if (threadIdx.x < 32) g_acc[threadIdx.x] = 0.0f;
}

// Fused: per-(c,h) slab — channel sums (S_ip, S_p) + conv along D + conv along W.
// Writes transposed g_bufT[c][w][h][d] so the H-conv kernel loads linearly.
__global__ void __launch_bounds__(256) convdw_sums_kernel(
        const float* __restrict__ labels, const float* __restrict__ img) {
    const int blk = blockIdx.x;          // c*SIDE + h
    const int c = blk / SIDE;
    const int h = blk % SIDE;
    const int n = c >> 2;
    __shared__ float tileA[SLAB];        // labels slab [w][d]
    __shared__ float tileB[SLAB];        // after d-conv
    const float4* lab4 = (const float4*)(labels + (size_t)blk * SLAB);
    const float4* img4 = (const float4*)(img + ((size_t)n * SIDE + h) * SLAB);
    float4* tA4 = (float4*)tileA;
    float sip = 0.f, sp = 0.f;
    for (int i = threadIdx.x; i < SLAB / 4; i += blockDim.x) {
        float4 l = lab4[i];
        float4 v = img4[i];
        sip += l.x * v.x + l.y * v.y + l.z * v.z + l.w * v.w;
        sp  += l.x + l.y + l.z + l.w;
        tA4[i] = l;
    }
    // block-reduce the two sums, one atomic pair per block
    #pragma unroll
    for (int off = 32; off > 0; off >>= 1) {
        sip += __shfl_down(sip, off);
        sp  += __shfl_down(sp, off);
    }
    __shared__ float sm[8];
    const int lane = threadIdx.x & 63;
    const int wid  = threadIdx.x >> 6;
    if (lane == 0) { sm[wid * 2] = sip; sm[wid * 2 + 1] = sp; }
    __syncthreads();
    if (threadIdx.x == 0) {
        atomicAdd(&g_acc[2 * c],     sm[0] + sm[2] + sm[4] + sm[6]);
        atomicAdd(&g_acc[2 * c + 1], sm[1] + sm[3] + sm[5] + sm[7]);
    }
    // conv along D (innermost): tileA -> tileB
    for (int i = threadIdx.x; i < SLAB; i += blockDim.x) {
        const int d = i % SIDE;
        float s = 0.f;
        #pragma unroll
        for (int t = -RAD; t <= RAD; ++t) {
            int dd = d + t;
            if (dd >= 0 && dd < SIDE) s += GW[t + RAD] * tileA[i + t];
        }
        tileB[i] = s;
    }
    __syncthreads();
    // conv along W: tileB -> g_bufT[c][w][h][d]
    float* outc = g_bufT + (size_t)c * VOL;
    for (int i = threadIdx.x; i < SLAB; i += blockDim.x) {
        const int w = i / SIDE;
        const int d = i - w * SIDE;
        float s = 0.f;
        #pragma unroll
        for (int t = -RAD; t <= RAD; ++t) {
            int ww = w + t;
            if (ww >= 0 && ww < SIDE) s += GW[t + RAD] * tileB[i + t * SIDE];
        }
        outc[(size_t)w * SLAB + (size_t)h * SIDE + d] = s;
    }
}

// Conv along H + fused weight + dot. Block per (c,w); g_bufT slab loads linearly.
// num_c = sum (G*lab)·lab·wgt ; den_c = sum (G*lab)·wgt, wgt = exp(-(img-mean_c)^4)
__global__ void __launch_bounds__(256) convh_dot_kernel(
        const float* __restrict__ labels, const float* __restrict__ img) {
    const int blk = blockIdx.x;      // c*SIDE + w
    const int c = blk / SIDE;
    const int w = blk % SIDE;
    const int n = c >> 2;
    const float mean = g_acc[2 * c] / (g_acc[2 * c + 1] + 5.12f);  // VOL*EPS_MEAN
    __shared__ float tile[SLAB];     // [h][d] of d+w-conv'd labels at fixed w
    const float4* bp4 = (const float4*)(g_bufT + (size_t)blk * SLAB);
    float4* t4 = (float4*)tile;
    for (int i = threadIdx.x; i < SLAB / 4; i += blockDim.x) t4[i] = bp4[i];
    __syncthreads();
    const float* labp = labels + (size_t)c * VOL;
    const float* imgp = img + (size_t)n * VOL;
    float num = 0.f, den = 0.f;
    for (int i = threadIdx.x; i < SLAB; i += blockDim.x) {
        int h = i / SIDE, d = i - h * SIDE;
        float s = 0.f;
        #pragma unroll
        for (int t = -RAD; t <= RAD; ++t) {
            int hh = h + t;
            if (hh >= 0 && hh < SIDE) s += GW[t + RAD] * tile[i + t * SIDE];
        }
        size_t gi = ((size_t)h * SIDE + w) * SIDE + d;
        float l = labp[gi];
        float v = imgp[gi];
        float df = v - mean;
        float d2 = df * df;
        float wgt = __expf(-d2 * d2);     // exp(-(img-mean)^4)
        num += s * l * wgt;
        den += s * wgt;
    }
    #pragma unroll
    for (int off = 32; off > 0; off >>= 1) {
        num += __shfl_down(num, off);
        den += __shfl_down(den, off);
    }
    __shared__ float sm[8];
    const int lane = threadIdx.x & 63;
    const int wid  = threadIdx.x >> 6;
    if (lane == 0) { sm[wid * 2] = num; sm[wid * 2 + 1] = den; }
    __syncthreads();
    if (threadIdx.x == 0) {
        atomicAdd(&g_acc[16 + 2 * c], sm[0] + sm[2] + sm[4] + sm[6]);
        atomicAdd(&g_acc[17 + 2 * c], sm[1] + sm[3] + sm[5] + sm[7]);
    }
}

__global__ void final_kernel(float* __restrict__ out) {
    if (threadIdx.x == 0) {
        float loss = 0.f;
        for (int k = 0; k < NCLS; ++k) {
            float r0 = g_acc[16 + 2 * k]          / (g_acc[17 + 2 * k] + 1e-6f);
            float r1 = g_acc[16 + 2 * (NCLS + k)] / (g_acc[17 + 2 * (NCLS + k)] + 1e-6f);
            loss += 0.5f * (fabsf(r0) + fabsf(r1));   // mean over N=2, sum over K
        }
        out[0] = (float)NCLS - loss;
    }
}

extern "C" void kernel_launch(void* const* d_in, const int* in_sizes, int n_in,
                              void* d_out, int out_size, void* d_ws, size_t ws_size,
                              hipStream_t stream) {
    const float* labels = (const float*)d_in[0];   // (2,4,80,80,80) f32
    const float* img    = (const float*)d_in[1];   // (2,1,80,80,80) f32
    float* out = (float*)d_out;                    // 1 float
    (void)d_ws; (void)ws_size;                     // unused — module-scope scratch

    hipLaunchKernelGGL(zero_acc_kernel, dim3(1), dim3(64), 0, stream);
    hipLaunchKernelGGL(convdw_sums_kernel, dim3(NCH * SIDE), dim3(256), 0, stream, labels, img);
    hipLaunchKernelGGL(convh_dot_kernel, dim3(NCH * SIDE), dim3(256), 0, stream, labels, img);
    hipLaunchKernelGGL(final_kernel, dim3(1), dim3(64), 0, stream, out);
}

// Round 5
// 101.684 us; speedup vs baseline: 1.5920x; 1.2936x over previous
//
#include <hip/hip_runtime.h>
#include <math.h>

#define RAD 5
#define SIDE 80
#define SLAB 6400      // 80*80
#define VOL 512000     // 80^3
#define NCH 8          // N*K
#define NCLS 4
#define TW 16          // tile extent along the convolved axis
#define NT 5           // tiles per axis (80/16)
#define CPART (SIDE*NT)        // 400 partials per channel
#define NBLK (NCH*SIDE*NT)     // 3200 blocks

// exp(-t^2/32) for t=-5..5 (unnormalized Gaussian, symmetric)
__constant__ float GW[11] = {
    0.45783336177161427f, 0.6065306597126334f, 0.7548396019890073f,
    0.8824969025845955f,  0.969233234476344f,  1.0f,
    0.969233234476344f,   0.8824969025845955f, 0.7548396019890073f,
    0.6065306597126334f,  0.45783336177161427f};

// Module-scope scratch (no d_ws dependence). All written-before-read each call.
__device__ float  g_bufT[(size_t)NCH * VOL];  // d+w-conv'd labels, [c][w][h][d]
__device__ float2 g_part1[NBLK];              // {S_ip, S_p} per K1 block
__device__ float2 g_part2[NBLK];              // {num, den} per K2 block

// K1: per (c, h, w-tile): channel sums + conv along D + conv along W,
// transposed store to g_bufT[c][w][h][d]. Halo rows zero-padded in LDS.
__global__ void __launch_bounds__(256) convdw_sums_kernel(
        const float* __restrict__ labels, const float* __restrict__ img) {
    const int blk = blockIdx.x;
    const int c   = blk / (SIDE * NT);
    const int rem = blk % (SIDE * NT);
    const int h   = rem / NT;
    const int w0  = (rem % NT) * TW;
    const int n   = c >> 2;

    __shared__ float tA[26 * 96];   // labels rows w0-5..w0+20; d padded by 8 cols each side-ish
    __shared__ float tB[26 * 80];   // d-conv output
    __shared__ float sm[8];

    // zero tA: covers OOB halo rows and d-padding columns
    float4* tA4 = (float4*)tA;
    for (int i = threadIdx.x; i < 26 * 96 / 4; i += 256) tA4[i] = make_float4(0.f, 0.f, 0.f, 0.f);
    __syncthreads();

    // load labels rows (row-granular range check; float4, aligned: 8-float col offset)
    const float* labc = labels + ((size_t)c * SIDE + h) * SLAB;   // [w][d] slab
    for (int i4 = threadIdx.x; i4 < 26 * 20; i4 += 256) {
        int r = i4 / 20, q = i4 - r * 20;
        int w = w0 - RAD + r;
        if (w >= 0 && w < SIDE) {
            ((float4*)(tA + r * 96 + 8))[q] = ((const float4*)(labc + (size_t)w * SIDE))[q];
        }
    }
    __syncthreads();

    // channel sums over the central 16 rows (img region is fully contiguous)
    float sip = 0.f, sp = 0.f;
    const float* imgc = img + ((((size_t)n * SIDE + h) * SIDE + w0) * SIDE);
    for (int i = threadIdx.x; i < TW * SIDE; i += 256) {
        int rl = i / SIDE, d = i - rl * SIDE;
        float l = tA[(rl + RAD) * 96 + 8 + d];
        float v = imgc[i];
        sip += l * v;
        sp  += l;
    }
    // conv along D for all 26 rows (branch-free: d-padding is zero)
    for (int i = threadIdx.x; i < 26 * SIDE; i += 256) {
        int r = i / SIDE, d = i - r * SIDE;
        const float* row = tA + r * 96 + 8 + d;
        float s = 0.f;
        #pragma unroll
        for (int t = -RAD; t <= RAD; ++t) s += GW[t + RAD] * row[t];
        tB[i] = s;
    }
    // reduce the sums (no atomics: per-block slot)
    #pragma unroll
    for (int off = 32; off > 0; off >>= 1) {
        sip += __shfl_down(sip, off);
        sp  += __shfl_down(sp, off);
    }
    const int lane = threadIdx.x & 63;
    const int wid  = threadIdx.x >> 6;
    if (lane == 0) { sm[wid * 2] = sip; sm[wid * 2 + 1] = sp; }
    __syncthreads();   // tB complete + sm visible
    if (threadIdx.x == 0)
        g_part1[blk] = make_float2(sm[0] + sm[2] + sm[4] + sm[6],
                                   sm[1] + sm[3] + sm[5] + sm[7]);
    // conv along W for the central 16 rows + transposed store
    float* outc = g_bufT + (size_t)c * VOL;
    for (int i = threadIdx.x; i < TW * SIDE; i += 256) {
        int rl = i / SIDE, d = i - rl * SIDE;
        float s = 0.f;
        #pragma unroll
        for (int t = -RAD; t <= RAD; ++t) s += GW[t + RAD] * tB[(rl + RAD + t) * SIDE + d];
        outc[(size_t)(w0 + rl) * SLAB + (size_t)h * SIDE + d] = s;
    }
}

// K2: per (c, w, h-tile): conv along H of g_bufT + fused weight + dot with labels.
// num_c = sum (G*lab)·lab·wgt ; den_c = sum (G*lab)·wgt ; wgt = exp(-(img-mean_c)^4)
__global__ void __launch_bounds__(256) convh_dot_kernel(
        const float* __restrict__ labels, const float* __restrict__ img) {
    const int blk = blockIdx.x;
    const int c   = blk / (SIDE * NT);
    const int rem = blk % (SIDE * NT);
    const int w   = rem / NT;
    const int h0  = (rem % NT) * TW;
    const int n   = c >> 2;

    __shared__ float tile[26 * 80];  // g_bufT rows h0-5..h0+20 at fixed (c,w)
    __shared__ float sm[8];
    __shared__ float s_mean;

    // per-channel mean from K1 partials (400 float2, L2-resident)
    float a = 0.f, b = 0.f;
    for (int t = threadIdx.x; t < CPART; t += 256) {
        float2 p = g_part1[c * CPART + t];
        a += p.x; b += p.y;
    }
    #pragma unroll
    for (int off = 32; off > 0; off >>= 1) {
        a += __shfl_down(a, off);
        b += __shfl_down(b, off);
    }
    const int lane = threadIdx.x & 63;
    const int wid  = threadIdx.x >> 6;
    if (lane == 0) { sm[wid * 2] = a; sm[wid * 2 + 1] = b; }

    // load tile (independent of the mean; rows contiguous in g_bufT layout)
    const float* bc = g_bufT + (size_t)c * VOL + (size_t)w * SLAB;
    for (int i4 = threadIdx.x; i4 < 26 * 20; i4 += 256) {
        int r = i4 / 20, q = i4 - r * 20;
        int hh = h0 - RAD + r;
        float4 v = (hh >= 0 && hh < SIDE)
                     ? ((const float4*)(bc + (size_t)hh * SIDE))[q]
                     : make_float4(0.f, 0.f, 0.f, 0.f);
        ((float4*)(tile + r * 80))[q] = v;
    }
    __syncthreads();
    if (threadIdx.x == 0)
        s_mean = (sm[0] + sm[2] + sm[4] + sm[6]) /
                 (sm[1] + sm[3] + sm[5] + sm[7] + 5.12f);   // VOL*EPS_MEAN
    __syncthreads();
    const float mean = s_mean;

    const float* labp = labels + (size_t)c * VOL;
    const float* imgp = img + (size_t)n * VOL;
    float num = 0.f, den = 0.f;
    for (int i = threadIdx.x; i < TW * SIDE; i += 256) {
        int hl = i / SIDE, d = i - hl * SIDE;
        float s = 0.f;
        #pragma unroll
        for (int t = 0; t <= 2 * RAD; ++t) s += GW[t] * tile[(hl + t) * SIDE + d];
        size_t gi = (((size_t)(h0 + hl) * SIDE + w) * SIDE) + d;
        float l = labp[gi];
        float v = imgp[gi];
        float df = v - mean;
        float d2 = df * df;
        float wgt = __expf(-d2 * d2);     // exp(-(img-mean)^4)
        num += s * l * wgt;
        den += s * wgt;
    }
    #pragma unroll
    for (int off = 32; off > 0; off >>= 1) {
        num += __shfl_down(num, off);
        den += __shfl_down(den, off);
    }
    if (lane == 0) { sm[wid * 2] = num; sm[wid * 2 + 1] = den; }
    __syncthreads();
    if (threadIdx.x == 0)
        g_part2[blk] = make_float2(sm[0] + sm[2] + sm[4] + sm[6],
                                   sm[1] + sm[3] + sm[5] + sm[7]);
}

// K3: reduce per-block partials -> per-channel ratio -> loss scalar
__global__ void __launch_bounds__(256) final_kernel(float* __restrict__ out) {
    __shared__ float sm[8];
    __shared__ float cn[NCH], cd[NCH];
    const int lane = threadIdx.x & 63;
    const int wid  = threadIdx.x >> 6;
    for (int c = 0; c < NCH; ++c) {
        float a = 0.f, b = 0.f;
        for (int t = threadIdx.x; t < CPART; t += 256) {
            float2 p = g_part2[c * CPART + t];
            a += p.x; b += p.y;
        }
        #pragma unroll
        for (int off = 32; off > 0; off >>= 1) {
            a += __shfl_down(a, off);
            b += __shfl_down(b, off);
        }
        if (lane == 0) { sm[wid * 2] = a; sm[wid * 2 + 1] = b; }
        __syncthreads();
        if (threadIdx.x == 0) {
            cn[c] = sm[0] + sm[2] + sm[4] + sm[6];
            cd[c] = sm[1] + sm[3] + sm[5] + sm[7];
        }
        __syncthreads();
    }
    if (threadIdx.x == 0) {
        float loss = 0.f;
        for (int k = 0; k < NCLS; ++k) {
            float r0 = cn[k]        / (cd[k]        + 1e-6f);
            float r1 = cn[NCLS + k] / (cd[NCLS + k] + 1e-6f);
            loss += 0.5f * (fabsf(r0) + fabsf(r1));   // mean over N=2, sum over K
        }
        out[0] = (float)NCLS - loss;
    }
}

extern "C" void kernel_launch(void* const* d_in, const int* in_sizes, int n_in,
                              void* d_out, int out_size, void* d_ws, size_t ws_size,
                              hipStream_t stream) {
    const float* labels = (const float*)d_in[0];   // (2,4,80,80,80) f32
    const float* img    = (const float*)d_in[1];   // (2,1,80,80,80) f32
    float* out = (float*)d_out;                    // 1 float
    (void)d_ws; (void)ws_size;                     // module-scope scratch

    hipLaunchKernelGGL(convdw_sums_kernel, dim3(NBLK), dim3(256), 0, stream, labels, img);
    hipLaunchKernelGGL(convh_dot_kernel,   dim3(NBLK), dim3(256), 0, stream, labels, img);
    hipLaunchKernelGGL(final_kernel,       dim3(1),    dim3(256), 0, stream, out);
}